// Round 8
// baseline (279.132 us; speedup 1.0000x reference)
//
#include <hip/hip_runtime.h>
#include <hip/hip_bf16.h>
#include <math.h>

typedef __attribute__((ext_vector_type(8))) short short8;
typedef __attribute__((ext_vector_type(8))) _Float16 half8;
typedef __attribute__((ext_vector_type(4))) float floatx4;
typedef const unsigned int __attribute__((address_space(1))) as1_cu32;
typedef unsigned int __attribute__((address_space(3))) as3_u32;

// ---------------- fp16 split helpers ----------------
__device__ __forceinline__ unsigned short h16(float x) {
  union { _Float16 f; unsigned short u; } c; c.f = (_Float16)x; return c.u;
}
__device__ __forceinline__ float h2f(unsigned short u) {
  union { _Float16 f; unsigned short u; } c; c.u = u; return (float)c.f;
}
__device__ __forceinline__ void hsplit(float x, unsigned short& h, unsigned short& l) {
  h = h16(x); l = h16(x - h2f(h));
}

// ---------------------------------------------------------------------------
// RoPE table
// ---------------------------------------------------------------------------
__global__ void rope_tab_kernel(float* __restrict__ tab) {
  int idx = blockIdx.x * 256 + threadIdx.x;
  if (idx >= 32768) return;
  int s  = idx >> 5, k2 = idx & 31;
  int r  = s >> 5,  c  = s & 31;
  int j  = k2 & 15;
  float f   = expf(-(float)j * (9.210340371976184f / 16.0f));
  float pos = (k2 < 16) ? (float)r : (float)c;
  float a   = pos * f;
  tab[2*idx]   = cosf(a);
  tab[2*idx+1] = sinf(a);
}

// ---------------------------------------------------------------------------
// x -> hi/lo fp16
// ---------------------------------------------------------------------------
__global__ __launch_bounds__(256) void xconv_kernel(
    const float* __restrict__ x, unsigned short* __restrict__ xh,
    unsigned short* __restrict__ xl) {
  int i = (blockIdx.x * 256 + threadIdx.x) * 4;
  float4 f = *(const float4*)&x[i];
  ushort4 h, l;
  hsplit(f.x, h.x, l.x); hsplit(f.y, h.y, l.y);
  hsplit(f.z, h.z, l.z); hsplit(f.w, h.w, l.w);
  *(ushort4*)&xh[i] = h;
  *(ushort4*)&xl[i] = l;
}

// ---------------------------------------------------------------------------
// W -> Wt single fp16 [N][K].  z=0,1,2 -> Wq,Wk,Wv into wt[2304][768]; z=3 -> Wo.
// ---------------------------------------------------------------------------
__global__ __launch_bounds__(256) void wconv_kernel(
    const float* __restrict__ Wq, const float* __restrict__ Wk,
    const float* __restrict__ Wv, const float* __restrict__ Wo,
    unsigned short* __restrict__ wt, unsigned short* __restrict__ wo) {
  __shared__ float tile[32][33];
  int z = blockIdx.z;
  const float* src = (z == 0) ? Wq : (z == 1) ? Wk : (z == 2) ? Wv : Wo;
  unsigned short* dh = (z < 3) ? wt + (size_t)z * 589824 : wo;
  int k0 = blockIdx.x * 32, n0 = blockIdx.y * 32;
  int tx = threadIdx.x & 31, ty = threadIdx.x >> 5;
#pragma unroll
  for (int r = 0; r < 4; ++r)
    tile[ty + r * 8][tx] = src[(size_t)(k0 + ty + r * 8) * 768 + n0 + tx];
  __syncthreads();
#pragma unroll
  for (int r = 0; r < 4; ++r) {
    int n = n0 + ty + r * 8;
    dh[(size_t)n * 768 + k0 + tx] = h16(tile[tx][ty + r * 8]);
  }
}

// ---------------------------------------------------------------------------
// Staging: one 128x32 fp16 plane via global_load_lds (XOR chunk swizzle).
// ---------------------------------------------------------------------------
__device__ __forceinline__ void stage_tile(const unsigned short* __restrict__ src,
                                           int row0, int k0, short* lds, int t) {
  int l  = t & 63;
  int wb = t & 192;
#pragma unroll
  for (int r = 0; r < 2; ++r) {
    int cbase = r * 256 + wb;
    int c = cbase + l;
    int m = c >> 2, s = c & 3;
    int g = s ^ (m & 3);
    const unsigned short* gp = src + (size_t)(row0 + m) * 768 + k0 + g * 8;
    __builtin_amdgcn_global_load_lds((as1_cu32*)(const void*)gp,
                                     (as3_u32*)(void*)(lds + cbase * 8),
                                     16, 0, 0);
  }
}
// 64x32 plane (256 chunks, 1 issue/thread)
__device__ __forceinline__ void stage_tile64(const unsigned short* __restrict__ src,
                                             int row0, int k0, short* lds, int t) {
  int c = t;
  int m = c >> 2, s = c & 3;
  int g = s ^ (m & 3);
  const unsigned short* gp = src + (size_t)(row0 + m) * 768 + k0 + g * 8;
  __builtin_amdgcn_global_load_lds((as1_cu32*)(const void*)gp,
                                   (as3_u32*)(void*)(lds + c * 8),
                                   16, 0, 0);
}

#define GEMM_MAIN_LOOP_DB(Ah, Al, Bs, m0, n0)                                    \
  floatx4 acc[4][4];                                                             \
  _Pragma("unroll") for (int i = 0; i < 4; ++i)                                  \
      _Pragma("unroll") for (int j = 0; j < 4; ++j)                              \
          acc[i][j] = (floatx4){0.f, 0.f, 0.f, 0.f};                             \
  const int l  = t & 63;                                                         \
  const int lm = l & 15, g = l >> 4;                                             \
  const int wm = ((t >> 7) & 1) * 64, wn = ((t >> 6) & 1) * 64;                  \
  const int sl = g ^ (lm & 3);                                                   \
  stage_tile(Ah, m0, 0, sAh, t);                                                 \
  stage_tile(Al, m0, 0, sAl, t);                                                 \
  stage_tile(Bs, n0, 0, sB, t);                                                  \
  for (int k0 = 0; k0 < 768; k0 += 32) {                                         \
    __syncthreads();                                                             \
    const int cur = (k0 >> 5) & 1, nxt = cur ^ 1;                                \
    if (k0 + 32 < 768) {                                                         \
      stage_tile(Ah, m0, k0 + 32, sAh + nxt * 4096, t);                          \
      stage_tile(Al, m0, k0 + 32, sAl + nxt * 4096, t);                          \
      stage_tile(Bs, n0, k0 + 32, sB  + nxt * 4096, t);                          \
    }                                                                            \
    const short* cAh = sAh + cur * 4096;                                         \
    const short* cAl = sAl + cur * 4096;                                         \
    const short* cB  = sB  + cur * 4096;                                         \
    half8 ah[4], al[4];                                                          \
    _Pragma("unroll") for (int i = 0; i < 4; ++i) {                              \
      int ra = wm + i * 16 + lm;                                                 \
      ah[i] = *(const half8*)&cAh[ra * 32 + sl * 8];                             \
      al[i] = *(const half8*)&cAl[ra * 32 + sl * 8];                             \
    }                                                                            \
    _Pragma("unroll") for (int j = 0; j < 4; ++j) {                              \
      int rb = wn + j * 16 + lm;                                                 \
      half8 b8 = *(const half8*)&cB[rb * 32 + sl * 8];                           \
      _Pragma("unroll") for (int i = 0; i < 4; ++i) {                            \
        acc[i][j] = __builtin_amdgcn_mfma_f32_16x16x32_f16(ah[i], b8, acc[i][j], 0, 0, 0); \
        acc[i][j] = __builtin_amdgcn_mfma_f32_16x16x32_f16(al[i], b8, acc[i][j], 0, 0, 0); \
      }                                                                          \
    }                                                                            \
  }

// ---------------------------------------------------------------------------
// Merged QKV projection: grid (64, 18); proj = n0/768 (0=q RoPE split,
// 1=k RoPE single, 2=v transpose -> V^T [B,H,64,S]).
// ---------------------------------------------------------------------------
__global__ __launch_bounds__(256) void qkv_mfma_kernel(
    const unsigned short* __restrict__ xh, const unsigned short* __restrict__ xl,
    const unsigned short* __restrict__ wt,
    const float* __restrict__ bq, const float* __restrict__ bk,
    const float* __restrict__ bv, const float* __restrict__ tab,
    unsigned short* __restrict__ qhp, unsigned short* __restrict__ qlp,
    unsigned short* __restrict__ khp, unsigned short* __restrict__ vtp) {
  __shared__ __align__(16) short smem[24576];
  short* sAh = smem;          short* sAl = smem + 8192;
  short* sB  = smem + 16384;
  const int t  = threadIdx.x;
  const int m0 = blockIdx.x * 128;
  const int n0 = blockIdx.y * 128;

  GEMM_MAIN_LOOP_DB(xh, xl, wt, m0, n0)

  const int proj = n0 / 768;
  const int col0 = n0 % 768;

  if (proj < 2) {
    const float* bias = (proj == 0) ? bq : bk;
    const float qs = (proj == 0) ? 0.125f : 1.f;
#pragma unroll
    for (int j = 0; j < 4; ++j) {
      int colf = col0 + wn + j * 16;
      int hh = colf >> 6;
      int d  = (colf & 63) + lm;
      float bsv = bias[colf + lm];
      int kidx = (d < 32) ? (d >> 1) : (16 + ((d - 32) >> 1));
      float sgn = (d & 1) ? 1.f : -1.f;
#pragma unroll
      for (int i = 0; i < 4; ++i) {
#pragma unroll
        for (int r = 0; r < 4; ++r) {
          int m = m0 + wm + i * 16 + g * 4 + r;
          int b = m >> 10, sidx = m & 1023;
          float val = acc[i][j][r] + bsv;
          float2 cssn = *(const float2*)&tab[(sidx * 32 + kidx) * 2];
          float p = __shfl_xor(val, 1);
          val = (val * cssn.x + sgn * (p * cssn.y)) * qs;
          size_t off = (((size_t)(b * 12 + hh)) * 1024 + sidx) * 64 + (d & ~1);
          if (proj == 0) {
            unsigned short hv, lv; hsplit(val, hv, lv);
            unsigned hx = (unsigned)__shfl_xor((int)hv, 1);
            unsigned lx = (unsigned)__shfl_xor((int)lv, 1);
            if ((lm & 1) == 0)
              *(unsigned*)&qhp[off] = ((hx & 0xffffu) << 16) | (unsigned)hv;
            else
              *(unsigned*)&qlp[off] = (((unsigned)lv) << 16) | (lx & 0xffffu);
          } else {
            unsigned short hv = h16(val);
            unsigned hx = (unsigned)__shfl_xor((int)hv, 1);
            if ((lm & 1) == 0)
              *(unsigned*)&khp[off] = ((hx & 0xffffu) << 16) | (unsigned)hv;
          }
        }
      }
    }
  } else {
    // ---- V: pack fp16, LDS-transpose (reuse smem[0..16383]), coalesced V^T ----
    uint2 hpk[4][4];
#pragma unroll
    for (int j = 0; j < 4; ++j) {
      float bsv = bv[col0 + wn + j * 16 + lm];
#pragma unroll
      for (int i = 0; i < 4; ++i) {
        unsigned short hv[4];
#pragma unroll
        for (int r = 0; r < 4; ++r) hv[r] = h16(acc[i][j][r] + bsv);
        hpk[i][j] = make_uint2((unsigned)hv[0] | ((unsigned)hv[1] << 16),
                               (unsigned)hv[2] | ((unsigned)hv[3] << 16));
      }
    }
    const int bidx = m0 >> 10;
    const int s0   = m0 & 1023;
    __syncthreads();
#pragma unroll
    for (int i = 0; i < 4; ++i)
#pragma unroll
      for (int j = 0; j < 4; ++j) {
        int n  = wn + j * 16 + lm;
        int mb = wm + i * 16 + g * 4;
        int chunk = mb >> 3;
        int cs = chunk ^ (n & 7);
        *(uint2*)&smem[n * 128 + cs * 8 + (g & 1) * 4] = hpk[i][j];
      }
    __syncthreads();
    {
      int nl = t >> 1, hf = t & 1;
      int colf = col0 + nl;
      int hh = colf >> 6, d = colf & 63;
      size_t rb = ((size_t)(bidx * 12 + hh) * 64 + d) * 1024 + s0;
#pragma unroll
      for (int cc = 0; cc < 8; ++cc) {
        int c = hf * 8 + cc;
        int cs = c ^ (nl & 7);
        *(short8*)&vtp[rb + c * 8] = *(const short8*)&smem[nl * 128 + cs * 8];
      }
    }
  }
}

// ---------------------------------------------------------------------------
// MFMA flash attention (fp16), DB K/VT staging, XCD-local (b,h) mapping,
// defer-max rescale (THR=8), setprio around MFMA clusters.
// ---------------------------------------------------------------------------
__global__ __launch_bounds__(256) void attn_mfma_kernel(
    const unsigned short* __restrict__ qhp, const unsigned short* __restrict__ qlp,
    const unsigned short* __restrict__ khp, const unsigned short* __restrict__ vtp,
    unsigned short* __restrict__ oh, unsigned short* __restrict__ ol) {
  __shared__ __align__(16) short sK[8192], sVT[8192];
  __shared__ __align__(16) short sP[4][2304];
  const int t  = threadIdx.x;
  const int wv = t >> 6, l = t & 63, lm = l & 15, g = l >> 4;
  // XCD-local remap: all 8 q-chunks of a (b,h), and 12 bh's, share one XCD
  // (assumes round-robin XCD assignment by blockIdx%8; perf-only, bijective).
  const int bid = blockIdx.x;
  const int bh  = (bid & 7) + ((bid >> 6) << 3);
  const int qw0 = ((bid >> 3) & 7) * 128 + wv * 32;

  half8 qfh[2][2], qfl[2][2];
#pragma unroll
  for (int i = 0; i < 2; ++i) {
    size_t base = ((size_t)bh * 1024 + qw0 + i * 16 + lm) * 64;
#pragma unroll
    for (int tt = 0; tt < 2; ++tt) {
      qfh[i][tt] = *(const half8*)&qhp[base + tt * 32 + g * 8];
      qfl[i][tt] = *(const half8*)&qlp[base + tt * 32 + g * 8];
    }
  }

  float mrun[2] = {-1e30f, -1e30f}, lrun[2] = {0.f, 0.f};
  floatx4 o[2][4];
#pragma unroll
  for (int i = 0; i < 2; ++i)
#pragma unroll
    for (int jd = 0; jd < 4; ++jd) o[i][jd] = (floatx4){0.f, 0.f, 0.f, 0.f};

  short* sPw = sP[wv];

  auto stage_kv = [&](int kt, int buf) {
#pragma unroll
    for (int qi = 0; qi < 4; ++qi) {
      int cz = qi * 256 + t;
      int plane = cz >> 9;
      int c = cz & 511;
      int row = c >> 3, s = c & 7;
      int gs = s ^ (row & 7);
      const unsigned short* gp = plane
          ? vtp + ((size_t)bh * 64 + row) * 1024 + kt * 64 + gs * 8
          : khp + ((size_t)bh * 1024 + kt * 64 + row) * 64 + gs * 8;
      short* dst = (plane ? sVT : sK) + buf * 4096 + c * 8;
      __builtin_amdgcn_global_load_lds((as1_cu32*)(const void*)gp,
                                       (as3_u32*)(void*)dst, 16, 0, 0);
    }
  };

  stage_kv(0, 0);

#pragma unroll 1
  for (int kt = 0; kt < 16; ++kt) {
    __syncthreads();
    const int cur = kt & 1, nxt = cur ^ 1;
    if (kt + 1 < 16) stage_kv(kt + 1, nxt);
    const short* cK  = sK  + cur * 4096;
    const short* cVT = sVT + cur * 4096;

    // ---- QK^T (2 terms, Q exact) ----
    floatx4 sacc[2][4];
#pragma unroll
    for (int i = 0; i < 2; ++i)
#pragma unroll
      for (int j = 0; j < 4; ++j) sacc[i][j] = (floatx4){0.f, 0.f, 0.f, 0.f};
    __builtin_amdgcn_s_setprio(1);
#pragma unroll
    for (int tt = 0; tt < 2; ++tt) {
#pragma unroll
      for (int j = 0; j < 4; ++j) {
        int row = j * 16 + lm;
        int so = ((4 * tt + g) ^ (row & 7)) * 8;
        half8 kf = *(const half8*)&cK[row * 64 + so];
#pragma unroll
        for (int i = 0; i < 2; ++i) {
          sacc[i][j] = __builtin_amdgcn_mfma_f32_16x16x32_f16(kf, qfh[i][tt], sacc[i][j], 0, 0, 0);
          sacc[i][j] = __builtin_amdgcn_mfma_f32_16x16x32_f16(kf, qfl[i][tt], sacc[i][j], 0, 0, 0);
        }
      }
    }
    __builtin_amdgcn_s_setprio(0);

    // ---- per-lane online softmax with defer-max (THR=8) ----
    float mt[2];
#pragma unroll
    for (int i = 0; i < 2; ++i) {
      float m_ = -1e30f;
#pragma unroll
      for (int j = 0; j < 4; ++j)
#pragma unroll
        for (int r = 0; r < 4; ++r) m_ = fmaxf(m_, sacc[i][j][r]);
      m_ = fmaxf(m_, __shfl_xor(m_, 16));
      m_ = fmaxf(m_, __shfl_xor(m_, 32));
      mt[i] = m_;
    }
    const bool skip = __all((mt[0] <= mrun[0] + 8.f) & (mt[1] <= mrun[1] + 8.f));
    float p[2][16];
#pragma unroll
    for (int i = 0; i < 2; ++i) {
      float mn, corr;
      if (skip) { mn = mrun[i]; corr = 1.f; }
      else { mn = fmaxf(mrun[i], mt[i]); corr = __expf(mrun[i] - mn); mrun[i] = mn; }
      float ps = 0.f;
#pragma unroll
      for (int j = 0; j < 4; ++j)
#pragma unroll
        for (int r = 0; r < 4; ++r) {
          float e = __expf(sacc[i][j][r] - mn);
          p[i][j * 4 + r] = e; ps += e;
        }
      ps += __shfl_xor(ps, 16);
      ps += __shfl_xor(ps, 32);
      lrun[i] = lrun[i] * corr + ps;
      if (!skip) {
#pragma unroll
        for (int jd = 0; jd < 4; ++jd)
#pragma unroll
          for (int r = 0; r < 4; ++r) o[i][jd][r] *= corr;
      }
    }

    // ---- P -> per-wave LDS (single fp16 plane) ----
#pragma unroll
    for (int i = 0; i < 2; ++i)
#pragma unroll
      for (int j = 0; j < 4; ++j) {
        unsigned short hv[4];
#pragma unroll
        for (int r = 0; r < 4; ++r) hv[r] = h16(p[i][j * 4 + r]);
        *(uint2*)&sPw[(i * 16 + lm) * 72 + j * 16 + g * 4] =
            make_uint2((unsigned)hv[0] | ((unsigned)hv[1] << 16),
                       (unsigned)hv[2] | ((unsigned)hv[3] << 16));
      }
    half8 pf[2][2];
#pragma unroll
    for (int i = 0; i < 2; ++i)
#pragma unroll
      for (int tt = 0; tt < 2; ++tt)
        pf[i][tt] = *(const half8*)&sPw[(i * 16 + lm) * 72 + tt * 32 + g * 8];

    // ---- PV (single term) ----
    __builtin_amdgcn_s_setprio(1);
#pragma unroll
    for (int tt = 0; tt < 2; ++tt) {
#pragma unroll
      for (int jd = 0; jd < 4; ++jd) {
        int row = jd * 16 + lm;
        int so = ((4 * tt + g) ^ (row & 7)) * 8;
        half8 vf = *(const half8*)&cVT[row * 64 + so];
#pragma unroll
        for (int i = 0; i < 2; ++i)
          o[i][jd] = __builtin_amdgcn_mfma_f32_16x16x32_f16(vf, pf[i][tt], o[i][jd], 0, 0, 0);
      }
    }
    __builtin_amdgcn_s_setprio(0);
  }

  // ---- epilogue: normalize, hi/lo fp16 out [B,S,768] ----
  const int b = bh / 12, h = bh % 12;
#pragma unroll
  for (int i = 0; i < 2; ++i) {
    float inv = 1.f / lrun[i];
    int q = qw0 + i * 16 + lm;
#pragma unroll
    for (int jd = 0; jd < 4; ++jd) {
      unsigned short hv[4], lv[4];
#pragma unroll
      for (int r = 0; r < 4; ++r) hsplit(o[i][jd][r] * inv, hv[r], lv[r]);
      size_t off = ((size_t)(b * 1024) + q) * 768 + h * 64 + jd * 16 + g * 4;
      *(uint2*)&oh[off] = make_uint2((unsigned)hv[0] | ((unsigned)hv[1] << 16),
                                     (unsigned)hv[2] | ((unsigned)hv[3] << 16));
      *(uint2*)&ol[off] = make_uint2((unsigned)lv[0] | ((unsigned)lv[1] << 16),
                                     (unsigned)lv[2] | ((unsigned)lv[3] << 16));
    }
  }
}

// ---------------------------------------------------------------------------
// Output projection, 64x128 tile (grid 128x6 = 768 blocks = 3/CU exact).
// 4 waves as 2(m)x2(n); wave-tile 32x64; acc[2][4]; LDS 32KB.
// ---------------------------------------------------------------------------
__global__ __launch_bounds__(256) void proj_mfma_kernel(
    const unsigned short* __restrict__ ah_, const unsigned short* __restrict__ al_,
    const unsigned short* __restrict__ wo_, const float* __restrict__ bo,
    float* __restrict__ out) {
  __shared__ __align__(16) short sAh[4096], sAl[4096], sB[8192];
  const int t  = threadIdx.x;
  const int m0 = blockIdx.x * 64;
  const int n0 = blockIdx.y * 128;

  floatx4 acc[2][4];
#pragma unroll
  for (int i = 0; i < 2; ++i)
#pragma unroll
    for (int j = 0; j < 4; ++j) acc[i][j] = (floatx4){0.f, 0.f, 0.f, 0.f};
  const int l  = t & 63;
  const int lm = l & 15, g = l >> 4;
  const int wm = ((t >> 7) & 1) * 32, wn = ((t >> 6) & 1) * 64;
  const int sl = g ^ (lm & 3);

  stage_tile64(ah_, m0, 0, sAh, t);
  stage_tile64(al_, m0, 0, sAl, t);
  stage_tile (wo_, n0, 0, sB,  t);

  for (int k0 = 0; k0 < 768; k0 += 32) {
    __syncthreads();
    const int cur = (k0 >> 5) & 1, nxt = cur ^ 1;
    if (k0 + 32 < 768) {
      stage_tile64(ah_, m0, k0 + 32, sAh + nxt * 2048, t);
      stage_tile64(al_, m0, k0 + 32, sAl + nxt * 2048, t);
      stage_tile (wo_, n0, k0 + 32, sB  + nxt * 4096, t);
    }
    const short* cAh = sAh + cur * 2048;
    const short* cAl = sAl + cur * 2048;
    const short* cB  = sB  + cur * 4096;
    half8 ah[2], al[2];
#pragma unroll
    for (int i = 0; i < 2; ++i) {
      int ra = wm + i * 16 + lm;
      ah[i] = *(const half8*)&cAh[ra * 32 + sl * 8];
      al[i] = *(const half8*)&cAl[ra * 32 + sl * 8];
    }
#pragma unroll
    for (int j = 0; j < 4; ++j) {
      int rb = wn + j * 16 + lm;
      half8 b8 = *(const half8*)&cB[rb * 32 + sl * 8];
#pragma unroll
      for (int i = 0; i < 2; ++i) {
        acc[i][j] = __builtin_amdgcn_mfma_f32_16x16x32_f16(ah[i], b8, acc[i][j], 0, 0, 0);
        acc[i][j] = __builtin_amdgcn_mfma_f32_16x16x32_f16(al[i], b8, acc[i][j], 0, 0, 0);
      }
    }
  }

#pragma unroll
  for (int j = 0; j < 4; ++j) {
    int n = n0 + wn + j * 16 + lm;
    float bsv = bo[n];
#pragma unroll
    for (int i = 0; i < 2; ++i) {
#pragma unroll
      for (int r = 0; r < 4; ++r) {
        int m = m0 + wm + i * 16 + g * 4 + r;
        out[(size_t)m * 768 + n] = acc[i][j][r] + bsv;
      }
    }
  }
}

// ---------------------------------------------------------------------------
extern "C" void kernel_launch(void* const* d_in, const int* in_sizes, int n_in,
                              void* d_out, int out_size, void* d_ws, size_t ws_size,
                              hipStream_t stream) {
  const float* x  = (const float*)d_in[0];
  const float* Wq = (const float*)d_in[1];
  const float* bq = (const float*)d_in[2];
  const float* Wk = (const float*)d_in[3];
  const float* bk = (const float*)d_in[4];
  const float* Wv = (const float*)d_in[5];
  const float* bv = (const float*)d_in[6];
  const float* Wo = (const float*)d_in[7];
  const float* bo = (const float*)d_in[8];
  float* out = (float*)d_out;

  char* w = (char*)d_ws;
  float* tab          = (float*)(w);                      // 262144
  unsigned short* wt  = (unsigned short*)(w + 262144);    // 3538944 (Wq|Wk|Wv ^T fp16)
  unsigned short* wo  = (unsigned short*)(w + 3801088);   // 1179648
  unsigned short* xh  = (unsigned short*)(w + 4980736);   // 12582912 (reused: attn out hi)
  unsigned short* xl  = (unsigned short*)(w + 17563648);  // 12582912 (reused: attn out lo)
  unsigned short* qh  = (unsigned short*)(w + 30146560);  // 12582912
  unsigned short* ql  = (unsigned short*)(w + 42729472);  // 12582912
  unsigned short* kh  = (unsigned short*)(w + 55312384);  // 12582912
  unsigned short* vt  = (unsigned short*)(w + 67895296);  // 12582912 -> end 80478208

  rope_tab_kernel<<<dim3(128), dim3(256), 0, stream>>>(tab);
  xconv_kernel<<<dim3(6144), dim3(256), 0, stream>>>(x, xh, xl);
  wconv_kernel<<<dim3(24, 24, 4), dim3(256), 0, stream>>>(
      Wq, Wk, Wv, Wo, wt, wo);
  qkv_mfma_kernel<<<dim3(64, 18), dim3(256), 0, stream>>>(
      xh, xl, wt, bq, bk, bv, tab, qh, ql, kh, vt);
  attn_mfma_kernel<<<dim3(768), dim3(256), 0, stream>>>(
      qh, ql, kh, vt, xh, xl);
  proj_mfma_kernel<<<dim3(128, 6), dim3(256), 0, stream>>>(
      xh, xl, wo, bo, out);
}

// Round 11
// 240.789 us; speedup vs baseline: 1.1592x; 1.1592x over previous
//
#include <hip/hip_runtime.h>
#include <hip/hip_bf16.h>
#include <math.h>

typedef __attribute__((ext_vector_type(8))) short short8;
typedef __attribute__((ext_vector_type(8))) _Float16 half8;
typedef __attribute__((ext_vector_type(4))) float floatx4;
typedef const unsigned int __attribute__((address_space(1))) as1_cu32;
typedef unsigned int __attribute__((address_space(3))) as3_u32;

// ---------------- fp16 helpers ----------------
__device__ __forceinline__ unsigned short h16(float x) {
  union { _Float16 f; unsigned short u; } c; c.f = (_Float16)x; return c.u;
}

// ---------------------------------------------------------------------------
// RoPE table
// ---------------------------------------------------------------------------
__global__ void rope_tab_kernel(float* __restrict__ tab) {
  int idx = blockIdx.x * 256 + threadIdx.x;
  if (idx >= 32768) return;
  int s  = idx >> 5, k2 = idx & 31;
  int r  = s >> 5,  c  = s & 31;
  int j  = k2 & 15;
  float f   = expf(-(float)j * (9.210340371976184f / 16.0f));
  float pos = (k2 < 16) ? (float)r : (float)c;
  float a   = pos * f;
  tab[2*idx]   = cosf(a);
  tab[2*idx+1] = sinf(a);
}

// ---------------------------------------------------------------------------
// x -> single fp16
// ---------------------------------------------------------------------------
__global__ __launch_bounds__(256) void xconv_kernel(
    const float* __restrict__ x, unsigned short* __restrict__ xh) {
  int i = (blockIdx.x * 256 + threadIdx.x) * 4;
  float4 f = *(const float4*)&x[i];
  ushort4 h;
  h.x = h16(f.x); h.y = h16(f.y); h.z = h16(f.z); h.w = h16(f.w);
  *(ushort4*)&xh[i] = h;
}

// ---------------------------------------------------------------------------
// W -> Wt single fp16 [N][K].  z=0,1,2 -> Wq,Wk,Wv into wt[2304][768]; z=3 -> Wo.
// ---------------------------------------------------------------------------
__global__ __launch_bounds__(256) void wconv_kernel(
    const float* __restrict__ Wq, const float* __restrict__ Wk,
    const float* __restrict__ Wv, const float* __restrict__ Wo,
    unsigned short* __restrict__ wt, unsigned short* __restrict__ wo) {
  __shared__ float tile[32][33];
  int z = blockIdx.z;
  const float* src = (z == 0) ? Wq : (z == 1) ? Wk : (z == 2) ? Wv : Wo;
  unsigned short* dh = (z < 3) ? wt + (size_t)z * 589824 : wo;
  int k0 = blockIdx.x * 32, n0 = blockIdx.y * 32;
  int tx = threadIdx.x & 31, ty = threadIdx.x >> 5;
#pragma unroll
  for (int r = 0; r < 4; ++r)
    tile[ty + r * 8][tx] = src[(size_t)(k0 + ty + r * 8) * 768 + n0 + tx];
  __syncthreads();
#pragma unroll
  for (int r = 0; r < 4; ++r) {
    int n = n0 + ty + r * 8;
    dh[(size_t)n * 768 + k0 + tx] = h16(tile[tx][ty + r * 8]);
  }
}

// ---------------------------------------------------------------------------
// Staging: one 128x32 fp16 plane via global_load_lds (XOR chunk swizzle).
// ---------------------------------------------------------------------------
__device__ __forceinline__ void stage_tile(const unsigned short* __restrict__ src,
                                           int row0, int k0, short* lds, int t) {
  int l  = t & 63;
  int wb = t & 192;
#pragma unroll
  for (int r = 0; r < 2; ++r) {
    int cbase = r * 256 + wb;
    int c = cbase + l;
    int m = c >> 2, s = c & 3;
    int g = s ^ (m & 3);
    const unsigned short* gp = src + (size_t)(row0 + m) * 768 + k0 + g * 8;
    __builtin_amdgcn_global_load_lds((as1_cu32*)(const void*)gp,
                                     (as3_u32*)(void*)(lds + cbase * 8),
                                     16, 0, 0);
  }
}
// 64x32 plane (256 chunks, 1 issue/thread)
__device__ __forceinline__ void stage_tile64(const unsigned short* __restrict__ src,
                                             int row0, int k0, short* lds, int t) {
  int c = t;
  int m = c >> 2, s = c & 3;
  int g = s ^ (m & 3);
  const unsigned short* gp = src + (size_t)(row0 + m) * 768 + k0 + g * 8;
  __builtin_amdgcn_global_load_lds((as1_cu32*)(const void*)gp,
                                   (as3_u32*)(void*)(lds + c * 8),
                                   16, 0, 0);
}

// Single-term fp16 GEMM main loop (128x128 tile, BK=32, 4 waves, DB staging)
#define GEMM_MAIN_LOOP_1T(As, Bs, m0, n0)                                        \
  floatx4 acc[4][4];                                                             \
  _Pragma("unroll") for (int i = 0; i < 4; ++i)                                  \
      _Pragma("unroll") for (int j = 0; j < 4; ++j)                              \
          acc[i][j] = (floatx4){0.f, 0.f, 0.f, 0.f};                             \
  const int l  = t & 63;                                                         \
  const int lm = l & 15, g = l >> 4;                                             \
  const int wm = ((t >> 7) & 1) * 64, wn = ((t >> 6) & 1) * 64;                  \
  const int sl = g ^ (lm & 3);                                                   \
  stage_tile(As, m0, 0, sA, t);                                                  \
  stage_tile(Bs, n0, 0, sB, t);                                                  \
  for (int k0 = 0; k0 < 768; k0 += 32) {                                         \
    __syncthreads();                                                             \
    const int cur = (k0 >> 5) & 1, nxt = cur ^ 1;                                \
    if (k0 + 32 < 768) {                                                         \
      stage_tile(As, m0, k0 + 32, sA + nxt * 4096, t);                           \
      stage_tile(Bs, n0, k0 + 32, sB + nxt * 4096, t);                           \
    }                                                                            \
    const short* cA = sA + cur * 4096;                                           \
    const short* cB = sB + cur * 4096;                                           \
    half8 af[4];                                                                 \
    _Pragma("unroll") for (int i = 0; i < 4; ++i)                                \
      af[i] = *(const half8*)&cA[(wm + i * 16 + lm) * 32 + sl * 8];              \
    _Pragma("unroll") for (int j = 0; j < 4; ++j) {                              \
      half8 b8 = *(const half8*)&cB[(wn + j * 16 + lm) * 32 + sl * 8];           \
      _Pragma("unroll") for (int i = 0; i < 4; ++i)                              \
        acc[i][j] = __builtin_amdgcn_mfma_f32_16x16x32_f16(af[i], b8, acc[i][j], 0, 0, 0); \
    }                                                                            \
  }

// ---------------------------------------------------------------------------
// Merged QKV projection: grid (64, 18); proj = n0/768 (0=q RoPE, 1=k RoPE,
// 2=v transpose -> V^T [B,H,64,S]). All outputs single fp16.
// ---------------------------------------------------------------------------
__global__ __launch_bounds__(256) void qkv_mfma_kernel(
    const unsigned short* __restrict__ xh, const unsigned short* __restrict__ wt,
    const float* __restrict__ bq, const float* __restrict__ bk,
    const float* __restrict__ bv, const float* __restrict__ tab,
    unsigned short* __restrict__ qhp, unsigned short* __restrict__ khp,
    unsigned short* __restrict__ vtp) {
  __shared__ __align__(16) short smem[16384];
  short* sA = smem;          short* sB = smem + 8192;
  const int t  = threadIdx.x;
  const int m0 = blockIdx.x * 128;
  const int n0 = blockIdx.y * 128;

  GEMM_MAIN_LOOP_1T(xh, wt, m0, n0)

  const int proj = n0 / 768;
  const int col0 = n0 % 768;

  if (proj < 2) {
    const float* bias = (proj == 0) ? bq : bk;
    const float qs = (proj == 0) ? 0.125f : 1.f;
    unsigned short* dst = (proj == 0) ? qhp : khp;
#pragma unroll
    for (int j = 0; j < 4; ++j) {
      int colf = col0 + wn + j * 16;
      int hh = colf >> 6;
      int d  = (colf & 63) + lm;
      float bsv = bias[colf + lm];
      int kidx = (d < 32) ? (d >> 1) : (16 + ((d - 32) >> 1));
      float sgn = (d & 1) ? 1.f : -1.f;
#pragma unroll
      for (int i = 0; i < 4; ++i) {
#pragma unroll
        for (int r = 0; r < 4; ++r) {
          int m = m0 + wm + i * 16 + g * 4 + r;
          int b = m >> 10, sidx = m & 1023;
          float val = acc[i][j][r] + bsv;
          float2 cssn = *(const float2*)&tab[(sidx * 32 + kidx) * 2];
          float p = __shfl_xor(val, 1);
          val = (val * cssn.x + sgn * (p * cssn.y)) * qs;
          unsigned short hv = h16(val);
          unsigned hx = (unsigned)__shfl_xor((int)hv, 1);
          size_t off = (((size_t)(b * 12 + hh)) * 1024 + sidx) * 64 + (d & ~1);
          if ((lm & 1) == 0)
            *(unsigned*)&dst[off] = ((hx & 0xffffu) << 16) | (unsigned)hv;
        }
      }
    }
  } else {
    // ---- V: pack fp16, LDS-transpose (reuse smem), coalesced V^T ----
    uint2 hpk[4][4];
#pragma unroll
    for (int j = 0; j < 4; ++j) {
      float bsv = bv[col0 + wn + j * 16 + lm];
#pragma unroll
      for (int i = 0; i < 4; ++i) {
        unsigned short hv[4];
#pragma unroll
        for (int r = 0; r < 4; ++r) hv[r] = h16(acc[i][j][r] + bsv);
        hpk[i][j] = make_uint2((unsigned)hv[0] | ((unsigned)hv[1] << 16),
                               (unsigned)hv[2] | ((unsigned)hv[3] << 16));
      }
    }
    const int bidx = m0 >> 10;
    const int s0   = m0 & 1023;
    __syncthreads();
#pragma unroll
    for (int i = 0; i < 4; ++i)
#pragma unroll
      for (int j = 0; j < 4; ++j) {
        int n  = wn + j * 16 + lm;
        int mb = wm + i * 16 + g * 4;
        int chunk = mb >> 3;
        int cs = chunk ^ (n & 7);
        *(uint2*)&smem[n * 128 + cs * 8 + (g & 1) * 4] = hpk[i][j];
      }
    __syncthreads();
    {
      int nl = t >> 1, hf = t & 1;
      int colf = col0 + nl;
      int hh = colf >> 6, d = colf & 63;
      size_t rb = ((size_t)(bidx * 12 + hh) * 64 + d) * 1024 + s0;
#pragma unroll
      for (int cc = 0; cc < 8; ++cc) {
        int c = hf * 8 + cc;
        int cs = c ^ (nl & 7);
        *(short8*)&vtp[rb + c * 8] = *(const short8*)&smem[nl * 128 + cs * 8];
      }
    }
  }
}

// ---------------------------------------------------------------------------
// MFMA flash attention (single fp16 Q,K,V,P), DB K/VT staging, XCD-local
// remap, defer-max (THR=8), setprio around MFMA clusters.
// ---------------------------------------------------------------------------
__global__ __launch_bounds__(256) void attn_mfma_kernel(
    const unsigned short* __restrict__ qhp, const unsigned short* __restrict__ khp,
    const unsigned short* __restrict__ vtp, unsigned short* __restrict__ oh) {
  __shared__ __align__(16) short sK[8192], sVT[8192];
  __shared__ __align__(16) short sP[4][2304];
  const int t  = threadIdx.x;
  const int wv = t >> 6, l = t & 63, lm = l & 15, g = l >> 4;
  const int bid = blockIdx.x;
  const int bh  = (bid & 7) + ((bid >> 6) << 3);
  const int qw0 = ((bid >> 3) & 7) * 128 + wv * 32;

  half8 qf[2][2];
#pragma unroll
  for (int i = 0; i < 2; ++i) {
    size_t base = ((size_t)bh * 1024 + qw0 + i * 16 + lm) * 64;
#pragma unroll
    for (int tt = 0; tt < 2; ++tt)
      qf[i][tt] = *(const half8*)&qhp[base + tt * 32 + g * 8];
  }

  float mrun[2] = {-1e30f, -1e30f}, lrun[2] = {0.f, 0.f};
  floatx4 o[2][4];
#pragma unroll
  for (int i = 0; i < 2; ++i)
#pragma unroll
    for (int jd = 0; jd < 4; ++jd) o[i][jd] = (floatx4){0.f, 0.f, 0.f, 0.f};

  short* sPw = sP[wv];

  auto stage_kv = [&](int kt, int buf) {
#pragma unroll
    for (int qi = 0; qi < 4; ++qi) {
      int cz = qi * 256 + t;
      int plane = cz >> 9;
      int c = cz & 511;
      int row = c >> 3, s = c & 7;
      int gs = s ^ (row & 7);
      const unsigned short* gp = plane
          ? vtp + ((size_t)bh * 64 + row) * 1024 + kt * 64 + gs * 8
          : khp + ((size_t)bh * 1024 + kt * 64 + row) * 64 + gs * 8;
      short* dst = (plane ? sVT : sK) + buf * 4096 + c * 8;
      __builtin_amdgcn_global_load_lds((as1_cu32*)(const void*)gp,
                                       (as3_u32*)(void*)dst, 16, 0, 0);
    }
  };

  stage_kv(0, 0);

#pragma unroll 1
  for (int kt = 0; kt < 16; ++kt) {
    __syncthreads();
    const int cur = kt & 1, nxt = cur ^ 1;
    if (kt + 1 < 16) stage_kv(kt + 1, nxt);
    const short* cK  = sK  + cur * 4096;
    const short* cVT = sVT + cur * 4096;

    // ---- QK^T (single term) ----
    floatx4 sacc[2][4];
#pragma unroll
    for (int i = 0; i < 2; ++i)
#pragma unroll
      for (int j = 0; j < 4; ++j) sacc[i][j] = (floatx4){0.f, 0.f, 0.f, 0.f};
    __builtin_amdgcn_s_setprio(1);
#pragma unroll
    for (int tt = 0; tt < 2; ++tt) {
#pragma unroll
      for (int j = 0; j < 4; ++j) {
        int row = j * 16 + lm;
        int so = ((4 * tt + g) ^ (row & 7)) * 8;
        half8 kf = *(const half8*)&cK[row * 64 + so];
#pragma unroll
        for (int i = 0; i < 2; ++i)
          sacc[i][j] = __builtin_amdgcn_mfma_f32_16x16x32_f16(kf, qf[i][tt], sacc[i][j], 0, 0, 0);
      }
    }
    __builtin_amdgcn_s_setprio(0);

    // ---- per-lane online softmax with defer-max (THR=8) ----
    float mt[2];
#pragma unroll
    for (int i = 0; i < 2; ++i) {
      float m_ = -1e30f;
#pragma unroll
      for (int j = 0; j < 4; ++j)
#pragma unroll
        for (int r = 0; r < 4; ++r) m_ = fmaxf(m_, sacc[i][j][r]);
      m_ = fmaxf(m_, __shfl_xor(m_, 16));
      m_ = fmaxf(m_, __shfl_xor(m_, 32));
      mt[i] = m_;
    }
    const bool skip = __all((mt[0] <= mrun[0] + 8.f) & (mt[1] <= mrun[1] + 8.f));
    float p[2][16];
#pragma unroll
    for (int i = 0; i < 2; ++i) {
      float mn, corr;
      if (skip) { mn = mrun[i]; corr = 1.f; }
      else { mn = fmaxf(mrun[i], mt[i]); corr = __expf(mrun[i] - mn); mrun[i] = mn; }
      float ps = 0.f;
#pragma unroll
      for (int j = 0; j < 4; ++j)
#pragma unroll
        for (int r = 0; r < 4; ++r) {
          float e = __expf(sacc[i][j][r] - mn);
          p[i][j * 4 + r] = e; ps += e;
        }
      ps += __shfl_xor(ps, 16);
      ps += __shfl_xor(ps, 32);
      lrun[i] = lrun[i] * corr + ps;
      if (!skip) {
#pragma unroll
        for (int jd = 0; jd < 4; ++jd)
#pragma unroll
          for (int r = 0; r < 4; ++r) o[i][jd][r] *= corr;
      }
    }

    // ---- P -> per-wave LDS (single fp16 plane) ----
#pragma unroll
    for (int i = 0; i < 2; ++i)
#pragma unroll
      for (int j = 0; j < 4; ++j) {
        unsigned short hv[4];
#pragma unroll
        for (int r = 0; r < 4; ++r) hv[r] = h16(p[i][j * 4 + r]);
        *(uint2*)&sPw[(i * 16 + lm) * 72 + j * 16 + g * 4] =
            make_uint2((unsigned)hv[0] | ((unsigned)hv[1] << 16),
                       (unsigned)hv[2] | ((unsigned)hv[3] << 16));
      }
    half8 pf[2][2];
#pragma unroll
    for (int i = 0; i < 2; ++i)
#pragma unroll
      for (int tt = 0; tt < 2; ++tt)
        pf[i][tt] = *(const half8*)&sPw[(i * 16 + lm) * 72 + tt * 32 + g * 8];

    // ---- PV (single term) ----
    __builtin_amdgcn_s_setprio(1);
#pragma unroll
    for (int tt = 0; tt < 2; ++tt) {
#pragma unroll
      for (int jd = 0; jd < 4; ++jd) {
        int row = jd * 16 + lm;
        int so = ((4 * tt + g) ^ (row & 7)) * 8;
        half8 vf = *(const half8*)&cVT[row * 64 + so];
#pragma unroll
        for (int i = 0; i < 2; ++i)
          o[i][jd] = __builtin_amdgcn_mfma_f32_16x16x32_f16(vf, pf[i][tt], o[i][jd], 0, 0, 0);
      }
    }
    __builtin_amdgcn_s_setprio(0);
  }

  // ---- epilogue: normalize, single fp16 out [B,S,768] ----
  const int b = bh / 12, h = bh % 12;
#pragma unroll
  for (int i = 0; i < 2; ++i) {
    float inv = 1.f / lrun[i];
    int q = qw0 + i * 16 + lm;
#pragma unroll
    for (int jd = 0; jd < 4; ++jd) {
      unsigned short hv[4];
#pragma unroll
      for (int r = 0; r < 4; ++r) hv[r] = h16(o[i][jd][r] * inv);
      size_t off = ((size_t)(b * 1024) + q) * 768 + h * 64 + jd * 16 + g * 4;
      *(uint2*)&oh[off] = make_uint2((unsigned)hv[0] | ((unsigned)hv[1] << 16),
                                     (unsigned)hv[2] | ((unsigned)hv[3] << 16));
    }
  }
}

// ---------------------------------------------------------------------------
// Output projection, 64x128 tile, single-term fp16. Grid 128x6.
// ---------------------------------------------------------------------------
__global__ __launch_bounds__(256) void proj_mfma_kernel(
    const unsigned short* __restrict__ ah_, const unsigned short* __restrict__ wo_,
    const float* __restrict__ bo, float* __restrict__ out) {
  __shared__ __align__(16) short sA[4096], sB[8192];
  const int t  = threadIdx.x;
  const int m0 = blockIdx.x * 64;
  const int n0 = blockIdx.y * 128;

  floatx4 acc[2][4];
#pragma unroll
  for (int i = 0; i < 2; ++i)
#pragma unroll
    for (int j = 0; j < 4; ++j) acc[i][j] = (floatx4){0.f, 0.f, 0.f, 0.f};
  const int l  = t & 63;
  const int lm = l & 15, g = l >> 4;
  const int wm = ((t >> 7) & 1) * 32, wn = ((t >> 6) & 1) * 64;
  const int sl = g ^ (lm & 3);

  stage_tile64(ah_, m0, 0, sA, t);
  stage_tile (wo_, n0, 0, sB, t);

  for (int k0 = 0; k0 < 768; k0 += 32) {
    __syncthreads();
    const int cur = (k0 >> 5) & 1, nxt = cur ^ 1;
    if (k0 + 32 < 768) {
      stage_tile64(ah_, m0, k0 + 32, sA + nxt * 2048, t);
      stage_tile (wo_, n0, k0 + 32, sB + nxt * 4096, t);
    }
    const short* cA = sA + cur * 2048;
    const short* cB = sB + cur * 4096;
    half8 af[2];
#pragma unroll
    for (int i = 0; i < 2; ++i)
      af[i] = *(const half8*)&cA[(wm + i * 16 + lm) * 32 + sl * 8];
#pragma unroll
    for (int j = 0; j < 4; ++j) {
      half8 b8 = *(const half8*)&cB[(wn + j * 16 + lm) * 32 + sl * 8];
#pragma unroll
      for (int i = 0; i < 2; ++i)
        acc[i][j] = __builtin_amdgcn_mfma_f32_16x16x32_f16(af[i], b8, acc[i][j], 0, 0, 0);
    }
  }

#pragma unroll
  for (int j = 0; j < 4; ++j) {
    int n = n0 + wn + j * 16 + lm;
    float bsv = bo[n];
#pragma unroll
    for (int i = 0; i < 2; ++i) {
#pragma unroll
      for (int r = 0; r < 4; ++r) {
        int m = m0 + wm + i * 16 + g * 4 + r;
        out[(size_t)m * 768 + n] = acc[i][j][r] + bsv;
      }
    }
  }
}

// ---------------------------------------------------------------------------
extern "C" void kernel_launch(void* const* d_in, const int* in_sizes, int n_in,
                              void* d_out, int out_size, void* d_ws, size_t ws_size,
                              hipStream_t stream) {
  const float* x  = (const float*)d_in[0];
  const float* Wq = (const float*)d_in[1];
  const float* bq = (const float*)d_in[2];
  const float* Wk = (const float*)d_in[3];
  const float* bk = (const float*)d_in[4];
  const float* Wv = (const float*)d_in[5];
  const float* bv = (const float*)d_in[6];
  const float* Wo = (const float*)d_in[7];
  const float* bo = (const float*)d_in[8];
  float* out = (float*)d_out;

  char* w = (char*)d_ws;
  float* tab          = (float*)(w);                      // 262144
  unsigned short* wt  = (unsigned short*)(w + 262144);    // 3538944 (Wq|Wk|Wv ^T fp16)
  unsigned short* wo  = (unsigned short*)(w + 3801088);   // 1179648
  unsigned short* xh  = (unsigned short*)(w + 4980736);   // 12582912 (reused: attn out)
  unsigned short* qh  = (unsigned short*)(w + 17563648);  // 12582912
  unsigned short* kh  = (unsigned short*)(w + 30146560);  // 12582912
  unsigned short* vt  = (unsigned short*)(w + 42729472);  // 12582912 -> end 55312384

  rope_tab_kernel<<<dim3(128), dim3(256), 0, stream>>>(tab);
  xconv_kernel<<<dim3(6144), dim3(256), 0, stream>>>(x, xh);
  wconv_kernel<<<dim3(24, 24, 4), dim3(256), 0, stream>>>(
      Wq, Wk, Wv, Wo, wt, wo);
  qkv_mfma_kernel<<<dim3(64, 18), dim3(256), 0, stream>>>(
      xh, wt, bq, bk, bv, tab, qh, kh, vt);
  attn_mfma_kernel<<<dim3(768), dim3(256), 0, stream>>>(qh, kh, vt, xh);
  proj_mfma_kernel<<<dim3(128, 6), dim3(256), 0, stream>>>(xh, wo, bo, out);
}